// Round 1
// baseline (213.925 us; speedup 1.0000x reference)
//
#include <hip/hip_runtime.h>
#include <hip/hip_bf16.h>
#include <stdint.h>

// Problem constants
#define HID 1024
#define SEQ 2048
#define BATCH 2
#define NHEADS 16
#define HEADDIM 64
#define MROWS (BATCH*SEQ)   // 4096

#define GAS __attribute__((address_space(1)))
#define LAS __attribute__((address_space(3)))

typedef __attribute__((ext_vector_type(8))) __bf16 bf16x8;
typedef __attribute__((ext_vector_type(4))) float f32x4;
typedef __attribute__((ext_vector_type(2))) uint32_t u32x2;

__device__ __forceinline__ ushort f2bf(float f) {
  union { float f; uint32_t u; } v; v.f = f;
  return (ushort)((v.u + 0x7FFFu + ((v.u >> 16) & 1u)) >> 16);
}

__device__ __forceinline__ void gl_lds16(const void* g, void* l) {
  __builtin_amdgcn_global_load_lds((const GAS void*)g, (LAS void*)l, 16, 0, 0);
}

// ---------------- weight fp32 -> bf16 convert ----------------
__global__ __launch_bounds__(256) void k_cvt(const float* __restrict__ Wq,
                                             const float* __restrict__ Wk,
                                             const float* __restrict__ Wv,
                                             const float* __restrict__ Wo,
                                             ushort* __restrict__ dst) {
  int mat = blockIdx.y;
  const float* src = (mat == 0) ? Wq : (mat == 1) ? Wk : (mat == 2) ? Wv : Wo;
  int off = (blockIdx.x * 256 + threadIdx.x) * 4;
  float4 v = *(const float4*)(src + off);
  ushort4 o;
  o.x = f2bf(v.x); o.y = f2bf(v.y); o.z = f2bf(v.z); o.w = f2bf(v.w);
  *(ushort4*)(dst + (size_t)mat * (HID * HID) + off) = o;
}

// ---------------- LayerNorm fp32 -> bf16 ----------------
__global__ __launch_bounds__(256) void k_ln(const float* __restrict__ x,
                                            const float* __restrict__ g,
                                            const float* __restrict__ b,
                                            ushort* __restrict__ xn) {
  int row = blockIdx.x;
  int t = threadIdx.x;
  const float* xr = x + (size_t)row * HID;
  float4 v = *(const float4*)(xr + t * 4);
  float s = v.x + v.y + v.z + v.w;
  float s2 = v.x * v.x + v.y * v.y + v.z * v.z + v.w * v.w;
  for (int m = 1; m < 64; m <<= 1) { s += __shfl_xor(s, m); s2 += __shfl_xor(s2, m); }
  __shared__ float ws[4], ws2[4];
  int wid = t >> 6;
  if ((t & 63) == 0) { ws[wid] = s; ws2[wid] = s2; }
  __syncthreads();
  s = ws[0] + ws[1] + ws[2] + ws[3];
  s2 = ws2[0] + ws2[1] + ws2[2] + ws2[3];
  float mu = s * (1.0f / HID);
  float var = s2 * (1.0f / HID) - mu * mu;
  float rstd = rsqrtf(var + 1e-5f);
  float4 gg = *(const float4*)(g + t * 4);
  float4 bb = *(const float4*)(b + t * 4);
  ushort4 o;
  o.x = f2bf((v.x - mu) * rstd * gg.x + bb.x);
  o.y = f2bf((v.y - mu) * rstd * gg.y + bb.y);
  o.z = f2bf((v.z - mu) * rstd * gg.z + bb.z);
  o.w = f2bf((v.w - mu) * rstd * gg.w + bb.w);
  *(ushort4*)(xn + (size_t)row * HID + t * 4) = o;
}

// ---------------- fused QKV GEMM ----------------
// Q pre-scaled by 0.125*log2(e). V written TRANSPOSED: [bh][d][s].
__global__ __launch_bounds__(256) void k_qkv(const ushort* __restrict__ xn,
                                             const ushort* __restrict__ wmat,
                                             const float* __restrict__ bq,
                                             const float* __restrict__ bk,
                                             const float* __restrict__ bv,
                                             ushort* __restrict__ qo,
                                             ushort* __restrict__ ko,
                                             ushort* __restrict__ vo) {
  __shared__ ushort As[128 * 32];
  __shared__ ushort Bs[128 * 32];
  int tid = threadIdx.x;
  int lane = tid & 63;
  int wv = tid >> 6;
  int quad = lane >> 4;
  int l16 = lane & 15;
  int m0 = blockIdx.x * 128;
  int ng = blockIdx.y * 128;
  int mat = ng >> 10;            // 0,1,2
  int nloc = ng & 1023;
  const ushort* wptr = wmat + (size_t)mat * (HID * HID) + (size_t)nloc * HID;
  const float* bias = (mat == 0) ? bq : (mat == 1) ? bk : bv;
  ushort* outp = (mat == 0) ? qo : (mat == 1) ? ko : vo;
  const float scl = (mat == 0) ? 0.18033688011112042f : 1.0f;

  int arow = tid >> 2;
  int acol = (tid & 3) * 8;
  int wm = (wv >> 1) * 64, wn = (wv & 1) * 64;

  f32x4 acc[4][4] = {};
  for (int k0 = 0; k0 < HID; k0 += 32) {
    __syncthreads();
    for (int t = 0; t < 2; t++) {
      gl_lds16(xn + (size_t)(m0 + t * 64 + arow) * HID + k0 + acol,
               As + t * 2048 + wv * 512);
      gl_lds16(wptr + (size_t)(t * 64 + arow) * HID + k0 + acol,
               Bs + t * 2048 + wv * 512);
    }
    __syncthreads();
    bf16x8 af[4], bfr[4];
    for (int i = 0; i < 4; i++)
      af[i] = *(const bf16x8*)&As[(wm + i * 16 + l16) * 32 + quad * 8];
    for (int n = 0; n < 4; n++)
      bfr[n] = *(const bf16x8*)&Bs[(wn + n * 16 + l16) * 32 + quad * 8];
    for (int i = 0; i < 4; i++)
      for (int n = 0; n < 4; n++)
        acc[i][n] = __builtin_amdgcn_mfma_f32_16x16x32_bf16(af[i], bfr[n], acc[i][n], 0, 0, 0);
  }
  float bv4[4];
  for (int n = 0; n < 4; n++) bv4[n] = bias[nloc + wn + n * 16 + l16];
  for (int i = 0; i < 4; i++) {
    int mrow = m0 + wm + i * 16 + quad * 4;
    for (int n = 0; n < 4; n++) {
      int col = nloc + wn + n * 16 + l16;
      int h = col >> 6, d = col & 63;
      for (int r = 0; r < 4; r++) {
        int m = mrow + r;
        int bidx = m >> 11, sidx = m & 2047;
        size_t dst;
        if (mat == 2)  // V transposed: [bh][d][s]
          dst = (((size_t)(bidx * NHEADS + h) * HEADDIM) + d) * SEQ + sidx;
        else
          dst = (((size_t)(bidx * NHEADS + h) * SEQ) + sidx) * HEADDIM + d;
        outp[dst] = f2bf((acc[i][n][r] + bv4[n]) * scl);
      }
    }
  }
}

// ---------------- flash attention (DMA staging, XOR-swizzled LDS, dbuf) ----------------
// OCCUPANCY RESTRUCTURE vs previous version: Q-tile 64 (was 128), each of 4
// waves owns 16 q-rows (was 32). Grid (SEQ/64=32, 32) = 1024 blocks = 4/CU;
// LDS 40 KB (K/V dbuf 32 KB + Psm 8 KB) -> 4 blocks/CU * 4 waves = 16 waves/CU
// (was 2 blocks/CU = 8 waves/CU, OccupancyPercent 17%). Same total MFMA/exp
// work; K/V staged 2x more in aggregate but that is L2-resident traffic.
// LDS layouts (16B granules, 8 granules per 64-elem row):
//   Ksm[buf][key][g]:  slot g holds K granule (g ^ ((key>>2)&7))
//   Vsm[buf][d][g]:    slot g holds V^T granule (g ^ (d&7))   (row = dim, cols = keys)
//   Psm[wave][row][g]: slot g holds P granule (g ^ (row&7)), row in 0..15
// QK B-frag column l16 mapped to key 4*l16+nt -> P pack is one b64 per r.
__global__ __launch_bounds__(256, 4) void k_attn(const ushort* __restrict__ Q,
                                                 const ushort* __restrict__ K,
                                                 const ushort* __restrict__ Vt,
                                                 ushort* __restrict__ ctx) {
  __shared__ ushort Ksm[2][64 * 64];
  __shared__ ushort Vsm[2][64 * 64];
  __shared__ ushort Psm[4][16 * 64];
  int tid = threadIdx.x, lane = tid & 63, wv = tid >> 6, quad = lane >> 4, l16 = lane & 15;
  int bh = blockIdx.y;
  int q0 = blockIdx.x * 64;
  const ushort* Qb = Q + ((size_t)bh * SEQ + q0 + wv * 16) * HEADDIM;
  const ushort* Kb = K + (size_t)bh * SEQ * HEADDIM;
  const ushort* Vb = Vt + (size_t)bh * HEADDIM * SEQ;   // [d][s]
  ushort* Pw = Psm[wv];

  // Q fragments (A-layout), already scaled by 0.125*log2e. 16 rows per wave.
  bf16x8 qf[2];
  for (int c = 0; c < 2; c++)
    qf[c] = *(const bf16x8*)(Qb + (size_t)l16 * HEADDIM + c * 32 + quad * 8);

  bf16x8 ones;
  for (int j = 0; j < 8; j++) ones[j] = (__bf16)1.0f;

  // staging source addresses (swizzled), per thread, tile-invariant parts
  int gsl = lane & 7;
  int rowA = wv * 8 + (lane >> 3);        // t=0 rows 0..31
  int rowB = 32 + wv * 8 + (lane >> 3);   // t=1 rows 32..63
  const ushort* kSrcA = Kb + rowA * HEADDIM + ((gsl ^ ((rowA >> 2) & 7)) * 8);
  const ushort* kSrcB = Kb + rowB * HEADDIM + ((gsl ^ ((rowB >> 2) & 7)) * 8);
  const ushort* vSrcA = Vb + (size_t)rowA * SEQ + ((gsl ^ (rowA & 7)) * 8);
  const ushort* vSrcB = Vb + (size_t)rowB * SEQ + ((gsl ^ (rowB & 7)) * 8);
  int ldsA = wv * 512;          // t=0 dest (ushort idx)
  int ldsB = 2048 + wv * 512;   // t=1 dest

  f32x4 Oa[4] = {};
  f32x4 Os = {};
  int fk = l16 & 7;   // common read-side swizzle key

  // prologue: stage tile 0 into buf 0
  gl_lds16(kSrcA, &Ksm[0][ldsA]);
  gl_lds16(kSrcB, &Ksm[0][ldsB]);
  gl_lds16(vSrcA, &Vsm[0][ldsA]);
  gl_lds16(vSrcB, &Vsm[0][ldsB]);
  __syncthreads();   // compiler drains vmcnt(0) here

  for (int kt = 0; kt < SEQ / 64; kt++) {
    int buf = kt & 1;
    if (kt + 1 < SEQ / 64) {   // prefetch next tile into other buffer
      int nb = buf ^ 1;
      size_t ko = (size_t)(kt + 1) * 64 * HEADDIM;   // K tile stride: 64 rows
      size_t vo = (size_t)(kt + 1) * 64;             // V^T tile stride: 64 cols
      gl_lds16(kSrcA + ko, &Ksm[nb][ldsA]);
      gl_lds16(kSrcB + ko, &Ksm[nb][ldsB]);
      gl_lds16(vSrcA + vo, &Vsm[nb][ldsA]);
      gl_lds16(vSrcB + vo, &Vsm[nb][ldsB]);
    }

    // S = Q K^T. Column l16 of frag nt = key 4*l16+nt.
    f32x4 sacc[4] = {};
    for (int nt = 0; nt < 4; nt++) {
      int krow = 4 * l16 + nt;           // krow>>2 == l16 (nt<4)
      for (int c = 0; c < 2; c++) {
        int kb = c * 4 + quad;
        bf16x8 kf = *(const bf16x8*)&Ksm[buf][krow * 64 + ((kb ^ fk) * 8)];
        sacc[nt] = __builtin_amdgcn_mfma_f32_16x16x32_bf16(qf[c], kf, sacc[nt], 0, 0, 0);
      }
    }

    // p = exp2(s) (fixed-max M=0), pack 4 adjacent keys -> one b64 per r
    for (int r = 0; r < 4; r++) {
      union { float f; uint32_t u; } p0, p1, p2, p3;
      p0.f = __builtin_amdgcn_exp2f(fminf(sacc[0][r], 80.f));
      p1.f = __builtin_amdgcn_exp2f(fminf(sacc[1][r], 80.f));
      p2.f = __builtin_amdgcn_exp2f(fminf(sacc[2][r], 80.f));
      p3.f = __builtin_amdgcn_exp2f(fminf(sacc[3][r], 80.f));
      uint32_t pk01 = __builtin_amdgcn_perm(p1.u, p0.u, 0x07060302u);
      uint32_t pk23 = __builtin_amdgcn_perm(p3.u, p2.u, 0x07060302u);
      int row = quad * 4 + r;
      // keys 4*l16..4*l16+3: granule l16>>1, half (l16&1)
      int idx = (row * 8 + ((l16 >> 1) ^ (row & 7))) * 8 + (l16 & 1) * 4;
      *(u32x2*)&Pw[idx] = (u32x2){pk01, pk23};
    }
    // per-wave P region: same-wave RAW ordered by lgkmcnt, no barrier

    // O += P V ; Os += P * ones
    for (int c = 0; c < 2; c++) {
      int kb = c * 4 + quad;
      bf16x8 pf0 = *(const bf16x8*)&Pw[(l16 * 8 + (kb ^ fk)) * 8];
      Os = __builtin_amdgcn_mfma_f32_16x16x32_bf16(pf0, ones, Os, 0, 0, 0);
      for (int nt = 0; nt < 4; nt++) {
        int d = nt * 16 + l16;
        bf16x8 vf = *(const bf16x8*)&Vsm[buf][d * 64 + ((kb ^ fk) * 8)];
        Oa[nt] = __builtin_amdgcn_mfma_f32_16x16x32_bf16(pf0, vf, Oa[nt], 0, 0, 0);
      }
    }
    __syncthreads();   // drains prefetch vmcnt + all waves done with buf before overwrite
  }

  // epilogue: ctx[b*2048+s][h*64+d] bf16
  int bidx = bh >> 4, h = bh & 15;
  for (int r = 0; r < 4; r++) {
    float inv = 1.0f / Os[r];
    int sidx = q0 + wv * 16 + quad * 4 + r;
    size_t base = ((size_t)(bidx * SEQ) + sidx) * HID + h * HEADDIM;
    for (int nt = 0; nt < 4; nt++)
      ctx[base + nt * 16 + l16] = f2bf(Oa[nt][r] * inv);
  }
}

// ---------------- output projection + bias + residual ----------------
__global__ __launch_bounds__(256) void k_oproj(const ushort* __restrict__ ctx,
                                               const ushort* __restrict__ wmat,
                                               const float* __restrict__ bo,
                                               const float* __restrict__ x,
                                               float* __restrict__ out) {
  __shared__ ushort As[128 * 32];
  __shared__ ushort Bs[128 * 32];
  int tid = threadIdx.x;
  int lane = tid & 63;
  int wv = tid >> 6;
  int quad = lane >> 4;
  int l16 = lane & 15;
  int m0 = blockIdx.x * 128;
  int n0 = blockIdx.y * 128;
  const ushort* wptr = wmat + (size_t)3 * (HID * HID) + (size_t)n0 * HID;  // Wo
  int arow = tid >> 2;
  int acol = (tid & 3) * 8;
  int wm = (wv >> 1) * 64, wn = (wv & 1) * 64;

  f32x4 acc[4][4] = {};
  for (int k0 = 0; k0 < HID; k0 += 32) {
    __syncthreads();
    for (int t = 0; t < 2; t++) {
      gl_lds16(ctx + (size_t)(m0 + t * 64 + arow) * HID + k0 + acol,
               As + t * 2048 + wv * 512);
      gl_lds16(wptr + (size_t)(t * 64 + arow) * HID + k0 + acol,
               Bs + t * 2048 + wv * 512);
    }
    __syncthreads();
    bf16x8 af[4], bfr[4];
    for (int i = 0; i < 4; i++)
      af[i] = *(const bf16x8*)&As[(wm + i * 16 + l16) * 32 + quad * 8];
    for (int n = 0; n < 4; n++)
      bfr[n] = *(const bf16x8*)&Bs[(wn + n * 16 + l16) * 32 + quad * 8];
    for (int i = 0; i < 4; i++)
      for (int n = 0; n < 4; n++)
        acc[i][n] = __builtin_amdgcn_mfma_f32_16x16x32_bf16(af[i], bfr[n], acc[i][n], 0, 0, 0);
  }
  float bv4[4];
  for (int n = 0; n < 4; n++) bv4[n] = bo[n0 + wn + n * 16 + l16];
  for (int i = 0; i < 4; i++) {
    int mrow = m0 + wm + i * 16 + quad * 4;
    for (int n = 0; n < 4; n++) {
      int col = n0 + wn + n * 16 + l16;
      for (int r = 0; r < 4; r++) {
        size_t idx = (size_t)(mrow + r) * HID + col;
        out[idx] = acc[i][n][r] + bv4[n] + x[idx];
      }
    }
  }
}

extern "C" void kernel_launch(void* const* d_in, const int* in_sizes, int n_in,
                              void* d_out, int out_size, void* d_ws, size_t ws_size,
                              hipStream_t stream) {
  const float* x    = (const float*)d_in[0];
  const float* Wq   = (const float*)d_in[1];
  const float* bq   = (const float*)d_in[2];
  const float* Wk   = (const float*)d_in[3];
  const float* bk   = (const float*)d_in[4];
  const float* Wv   = (const float*)d_in[5];
  const float* bv   = (const float*)d_in[6];
  const float* Wo   = (const float*)d_in[7];
  const float* bo   = (const float*)d_in[8];
  const float* ln_g = (const float*)d_in[9];
  const float* ln_b = (const float*)d_in[10];
  float* out = (float*)d_out;

  const size_t MB = 1024 * 1024;
  ushort* ws_w = (ushort*)d_ws;                         // weights bf16, 8 MB
  ushort* xn   = (ushort*)((char*)d_ws + 8 * MB);
  ushort* Qw   = (ushort*)((char*)d_ws + 16 * MB);
  ushort* Kw   = (ushort*)((char*)d_ws + 24 * MB);
  ushort* Vw   = (ushort*)((char*)d_ws + 32 * MB);      // transposed [bh][d][s]
  ushort* Cw   = (ushort*)((char*)d_ws + 40 * MB);

  k_cvt<<<dim3(1024, 4), 256, 0, stream>>>(Wq, Wk, Wv, Wo, ws_w);
  k_ln<<<dim3(MROWS), 256, 0, stream>>>(x, ln_g, ln_b, xn);
  k_qkv<<<dim3(32, 24), 256, 0, stream>>>(xn, ws_w, bq, bk, bv, Qw, Kw, Vw);
  k_attn<<<dim3(SEQ / 64, BATCH * NHEADS), 256, 0, stream>>>(Qw, Kw, Vw, Cw);
  k_oproj<<<dim3(32, 8), 256, 0, stream>>>(Cw, ws_w, bo, x, out);
}

// Round 2
// 208.253 us; speedup vs baseline: 1.0272x; 1.0272x over previous
//
#include <hip/hip_runtime.h>
#include <hip/hip_bf16.h>
#include <stdint.h>

// Problem constants
#define HID 1024
#define SEQ 2048
#define BATCH 2
#define NHEADS 16
#define HEADDIM 64
#define MROWS (BATCH*SEQ)   // 4096

#define GAS __attribute__((address_space(1)))
#define LAS __attribute__((address_space(3)))

typedef __attribute__((ext_vector_type(8))) __bf16 bf16x8;
typedef __attribute__((ext_vector_type(4))) float f32x4;
typedef __attribute__((ext_vector_type(16))) float f32x16;

__device__ __forceinline__ ushort f2bf(float f) {
  union { float f; uint32_t u; } v; v.f = f;
  return (ushort)((v.u + 0x7FFFu + ((v.u >> 16) & 1u)) >> 16);
}

__device__ __forceinline__ void gl_lds16(const void* g, void* l) {
  __builtin_amdgcn_global_load_lds((const GAS void*)g, (LAS void*)l, 16, 0, 0);
}

// pack 2 f32 -> 2 bf16 in one u32 (lo = a, hi = b), RNE
__device__ __forceinline__ uint32_t cvtpk(float a, float b) {
  uint32_t r;
  asm("v_cvt_pk_bf16_f32 %0, %1, %2" : "=v"(r) : "v"(a), "v"(b));
  return r;
}

// swap: a_hi <-> b_lo  =>  a' = [a_lo, b_lo], b' = [a_hi, b_hi]
__device__ __forceinline__ void pl32swap(uint32_t& a, uint32_t& b) {
  asm("v_permlane32_swap_b32 %0, %1" : "+v"(a), "+v"(b));
}

// ---------------- weight fp32 -> bf16 convert ----------------
__global__ __launch_bounds__(256) void k_cvt(const float* __restrict__ Wq,
                                             const float* __restrict__ Wk,
                                             const float* __restrict__ Wv,
                                             const float* __restrict__ Wo,
                                             ushort* __restrict__ dst) {
  int mat = blockIdx.y;
  const float* src = (mat == 0) ? Wq : (mat == 1) ? Wk : (mat == 2) ? Wv : Wo;
  int off = (blockIdx.x * 256 + threadIdx.x) * 4;
  float4 v = *(const float4*)(src + off);
  ushort4 o;
  o.x = f2bf(v.x); o.y = f2bf(v.y); o.z = f2bf(v.z); o.w = f2bf(v.w);
  *(ushort4*)(dst + (size_t)mat * (HID * HID) + off) = o;
}

// ---------------- LayerNorm fp32 -> bf16 ----------------
__global__ __launch_bounds__(256) void k_ln(const float* __restrict__ x,
                                            const float* __restrict__ g,
                                            const float* __restrict__ b,
                                            ushort* __restrict__ xn) {
  int row = blockIdx.x;
  int t = threadIdx.x;
  const float* xr = x + (size_t)row * HID;
  float4 v = *(const float4*)(xr + t * 4);
  float s = v.x + v.y + v.z + v.w;
  float s2 = v.x * v.x + v.y * v.y + v.z * v.z + v.w * v.w;
  for (int m = 1; m < 64; m <<= 1) { s += __shfl_xor(s, m); s2 += __shfl_xor(s2, m); }
  __shared__ float ws[4], ws2[4];
  int wid = t >> 6;
  if ((t & 63) == 0) { ws[wid] = s; ws2[wid] = s2; }
  __syncthreads();
  s = ws[0] + ws[1] + ws[2] + ws[3];
  s2 = ws2[0] + ws2[1] + ws2[2] + ws2[3];
  float mu = s * (1.0f / HID);
  float var = s2 * (1.0f / HID) - mu * mu;
  float rstd = rsqrtf(var + 1e-5f);
  float4 gg = *(const float4*)(g + t * 4);
  float4 bb = *(const float4*)(b + t * 4);
  ushort4 o;
  o.x = f2bf((v.x - mu) * rstd * gg.x + bb.x);
  o.y = f2bf((v.y - mu) * rstd * gg.y + bb.y);
  o.z = f2bf((v.z - mu) * rstd * gg.z + bb.z);
  o.w = f2bf((v.w - mu) * rstd * gg.w + bb.w);
  *(ushort4*)(xn + (size_t)row * HID + t * 4) = o;
}

// ---------------- fused QKV GEMM ----------------
// Q pre-scaled by 0.125*log2(e). V written TRANSPOSED: [bh][d][s].
__global__ __launch_bounds__(256) void k_qkv(const ushort* __restrict__ xn,
                                             const ushort* __restrict__ wmat,
                                             const float* __restrict__ bq,
                                             const float* __restrict__ bk,
                                             const float* __restrict__ bv,
                                             ushort* __restrict__ qo,
                                             ushort* __restrict__ ko,
                                             ushort* __restrict__ vo) {
  __shared__ ushort As[128 * 32];
  __shared__ ushort Bs[128 * 32];
  int tid = threadIdx.x;
  int lane = tid & 63;
  int wv = tid >> 6;
  int quad = lane >> 4;
  int l16 = lane & 15;
  int m0 = blockIdx.x * 128;
  int ng = blockIdx.y * 128;
  int mat = ng >> 10;            // 0,1,2
  int nloc = ng & 1023;
  const ushort* wptr = wmat + (size_t)mat * (HID * HID) + (size_t)nloc * HID;
  const float* bias = (mat == 0) ? bq : (mat == 1) ? bk : bv;
  ushort* outp = (mat == 0) ? qo : (mat == 1) ? ko : vo;
  const float scl = (mat == 0) ? 0.18033688011112042f : 1.0f;

  int arow = tid >> 2;
  int acol = (tid & 3) * 8;
  int wm = (wv >> 1) * 64, wn = (wv & 1) * 64;

  f32x4 acc[4][4] = {};
  for (int k0 = 0; k0 < HID; k0 += 32) {
    __syncthreads();
    for (int t = 0; t < 2; t++) {
      gl_lds16(xn + (size_t)(m0 + t * 64 + arow) * HID + k0 + acol,
               As + t * 2048 + wv * 512);
      gl_lds16(wptr + (size_t)(t * 64 + arow) * HID + k0 + acol,
               Bs + t * 2048 + wv * 512);
    }
    __syncthreads();
    bf16x8 af[4], bfr[4];
    for (int i = 0; i < 4; i++)
      af[i] = *(const bf16x8*)&As[(wm + i * 16 + l16) * 32 + quad * 8];
    for (int n = 0; n < 4; n++)
      bfr[n] = *(const bf16x8*)&Bs[(wn + n * 16 + l16) * 32 + quad * 8];
    for (int i = 0; i < 4; i++)
      for (int n = 0; n < 4; n++)
        acc[i][n] = __builtin_amdgcn_mfma_f32_16x16x32_bf16(af[i], bfr[n], acc[i][n], 0, 0, 0);
  }
  float bv4[4];
  for (int n = 0; n < 4; n++) bv4[n] = bias[nloc + wn + n * 16 + l16];
  for (int i = 0; i < 4; i++) {
    int mrow = m0 + wm + i * 16 + quad * 4;
    for (int n = 0; n < 4; n++) {
      int col = nloc + wn + n * 16 + l16;
      int h = col >> 6, d = col & 63;
      for (int r = 0; r < 4; r++) {
        int m = mrow + r;
        int bidx = m >> 11, sidx = m & 2047;
        size_t dst;
        if (mat == 2)  // V transposed: [bh][d][s]
          dst = (((size_t)(bidx * NHEADS + h) * HEADDIM) + d) * SEQ + sidx;
        else
          dst = (((size_t)(bidx * NHEADS + h) * SEQ) + sidx) * HEADDIM + d;
        outp[dst] = f2bf((acc[i][n][r] + bv4[n]) * scl);
      }
    }
  }
}

// ---------------- flash attention v3: swapped-QK 32x32 MFMA, in-register P ----------------
// Geometry reverted to 128-row Q-tile (round-1's 64-row tile REGRESSED: occupancy
// doubled but MfmaUtil stuck at 24% -> not occupancy-bound; LDS traffic per q-row
// went UP). This version removes the P LDS round-trip (T12):
//   QK^T computed SWAPPED: S^T = mfma_32x32x16(A=K, B=Q) so C-layout gives
//   col=lane&31 = q-row  ->  each lane owns 32 key-scores of ITS q-row in regs.
//   exp2 -> v_cvt_pk_bf16_f32 -> v_permlane32_swap redistributes hi/lo key halves
//   into PV A-fragments entirely in registers. No Psm, no ds_write/ds_read of P,
//   no lgkm latency between softmax and PV.
// LDS: K/V double-buffered, 32 KB. 16 ds_read_b128 per wave-tile (was 26 DS ops).
// Fragment layouts (32x32x16): A: row=lane&31, k=(lane>>5)*8+j (8 contiguous k).
//   B: col=lane&31, k=(lane>>5)*8+j.  C/D: col=lane&31, row=(r&3)+8*(r>>2)+4*(lane>>5).
// LDS swizzle: granule slot g^(row&7) for both K [key][d] and V^T [d][key]
//   (reads walk 32 consecutive rows at one granule -> 8-lane groups hit 8 distinct
//    slots = 32 banks, conflict-free).
__global__ __launch_bounds__(256, 2) void k_attn(const ushort* __restrict__ Q,
                                                 const ushort* __restrict__ K,
                                                 const ushort* __restrict__ Vt,
                                                 ushort* __restrict__ ctx) {
  __shared__ ushort Ksm[2][64 * 64];
  __shared__ ushort Vsm[2][64 * 64];
  int tid = threadIdx.x, lane = tid & 63, wv = tid >> 6;
  int l32 = lane & 31, hi = lane >> 5;
  int bh = blockIdx.y;
  int q0 = blockIdx.x * 128;
  const ushort* Qb = Q + ((size_t)bh * SEQ + q0 + wv * 32 + l32) * HEADDIM;
  const ushort* Kb = K + (size_t)bh * SEQ * HEADDIM;
  const ushort* Vb = Vt + (size_t)bh * HEADDIM * SEQ;   // [d][s]

  // Q as B-frag: col=l32 (q-row), k(d) = f*16 + hi*8 + j. Pre-scaled by 0.125*log2e.
  bf16x8 qf[4];
#pragma unroll
  for (int f = 0; f < 4; f++)
    qf[f] = *(const bf16x8*)(Qb + f * 16 + hi * 8);

  bf16x8 ones;
#pragma unroll
  for (int j = 0; j < 8; j++) ones[j] = (__bf16)1.0f;

  // staging source addresses (pre-swizzled): linear LDS dest row = wv*8+(lane>>3),
  // slot = lane&7; we want logical granule g at slot g^(row&7) -> source granule
  // index = slot ^ (row&7).
  int gsl = lane & 7;
  int rowA = wv * 8 + (lane >> 3);        // rows 0..31
  int rowB = 32 + wv * 8 + (lane >> 3);   // rows 32..63
  const ushort* kSrcA = Kb + rowA * HEADDIM + ((gsl ^ (rowA & 7)) * 8);
  const ushort* kSrcB = Kb + rowB * HEADDIM + ((gsl ^ (rowB & 7)) * 8);
  const ushort* vSrcA = Vb + (size_t)rowA * SEQ + ((gsl ^ (rowA & 7)) * 8);
  const ushort* vSrcB = Vb + (size_t)rowB * SEQ + ((gsl ^ (rowB & 7)) * 8);
  int ldsA = wv * 512;          // ushort idx (1 KB per wave-issue)
  int ldsB = 2048 + wv * 512;

  f32x16 Oa0 = {}, Oa1 = {}, Os = {};
  int rsw = (l32 & 7);   // read-side swizzle key (row&7 for rows l32 and 32+l32)

  // prologue: stage tile 0 into buf 0
  gl_lds16(kSrcA, &Ksm[0][ldsA]);
  gl_lds16(kSrcB, &Ksm[0][ldsB]);
  gl_lds16(vSrcA, &Vsm[0][ldsA]);
  gl_lds16(vSrcB, &Vsm[0][ldsB]);
  __syncthreads();   // compiler drains vmcnt(0) here

  for (int kt = 0; kt < SEQ / 64; kt++) {
    int buf = kt & 1;
    if (kt + 1 < SEQ / 64) {   // prefetch next tile into other buffer
      int nb = buf ^ 1;
      size_t ko = (size_t)(kt + 1) * 64 * HEADDIM;
      size_t vo = (size_t)(kt + 1) * 64;
      gl_lds16(kSrcA + ko, &Ksm[nb][ldsA]);
      gl_lds16(kSrcB + ko, &Ksm[nb][ldsB]);
      gl_lds16(vSrcA + vo, &Vsm[nb][ldsA]);
      gl_lds16(vSrcB + vo, &Vsm[nb][ldsB]);
    }

    // S^T = K Q^T : A = K rows (keys), B = Q cols (q-rows).
    // s0 = keys 0..31, s1 = keys 32..63. Per lane: q-row l32,
    // key(kg,r) = kg*32 + (r&3) + 8*(r>>2) + 4*hi.
    f32x16 s0 = {}, s1 = {};
    __builtin_amdgcn_s_setprio(1);
#pragma unroll
    for (int f = 0; f < 4; f++) {
      int g = 2 * f + hi;
      bf16x8 k0 = *(const bf16x8*)&Ksm[buf][l32 * 64 + ((g ^ rsw) * 8)];
      bf16x8 k1 = *(const bf16x8*)&Ksm[buf][(32 + l32) * 64 + ((g ^ rsw) * 8)];
      s0 = __builtin_amdgcn_mfma_f32_32x32x16_bf16(k0, qf[f], s0, 0, 0, 0);
      s1 = __builtin_amdgcn_mfma_f32_32x32x16_bf16(k1, qf[f], s1, 0, 0, 0);
    }
    __builtin_amdgcn_s_setprio(0);

    // p = exp2(s) (fixed-max M=0), pack to bf16, permlane-redistribute into
    // PV A-frags pf[kf]: row=q (l32), k = keys kf*16 + hi*8 + j.
    union { uint32_t u[4]; bf16x8 v; } pf0, pf1, pf2, pf3;
    {
      uint32_t c0 = cvtpk(__builtin_amdgcn_exp2f(fminf(s0[0], 80.f)),
                          __builtin_amdgcn_exp2f(fminf(s0[1], 80.f)));
      uint32_t c1 = cvtpk(__builtin_amdgcn_exp2f(fminf(s0[2], 80.f)),
                          __builtin_amdgcn_exp2f(fminf(s0[3], 80.f)));
      uint32_t c2 = cvtpk(__builtin_amdgcn_exp2f(fminf(s0[4], 80.f)),
                          __builtin_amdgcn_exp2f(fminf(s0[5], 80.f)));
      uint32_t c3 = cvtpk(__builtin_amdgcn_exp2f(fminf(s0[6], 80.f)),
                          __builtin_amdgcn_exp2f(fminf(s0[7], 80.f)));
      uint32_t c4 = cvtpk(__builtin_amdgcn_exp2f(fminf(s0[8], 80.f)),
                          __builtin_amdgcn_exp2f(fminf(s0[9], 80.f)));
      uint32_t c5 = cvtpk(__builtin_amdgcn_exp2f(fminf(s0[10], 80.f)),
                          __builtin_amdgcn_exp2f(fminf(s0[11], 80.f)));
      uint32_t c6 = cvtpk(__builtin_amdgcn_exp2f(fminf(s0[12], 80.f)),
                          __builtin_amdgcn_exp2f(fminf(s0[13], 80.f)));
      uint32_t c7 = cvtpk(__builtin_amdgcn_exp2f(fminf(s0[14], 80.f)),
                          __builtin_amdgcn_exp2f(fminf(s0[15], 80.f)));
      pl32swap(c0, c2); pl32swap(c1, c3); pl32swap(c4, c6); pl32swap(c5, c7);
      pf0.u[0] = c0; pf0.u[1] = c1; pf0.u[2] = c2; pf0.u[3] = c3;
      pf1.u[0] = c4; pf1.u[1] = c5; pf1.u[2] = c6; pf1.u[3] = c7;
    }
    {
      uint32_t c0 = cvtpk(__builtin_amdgcn_exp2f(fminf(s1[0], 80.f)),
                          __builtin_amdgcn_exp2f(fminf(s1[1], 80.f)));
      uint32_t c1 = cvtpk(__builtin_amdgcn_exp2f(fminf(s1[2], 80.f)),
                          __builtin_amdgcn_exp2f(fminf(s1[3], 80.f)));
      uint32_t c2 = cvtpk(__builtin_amdgcn_exp2f(fminf(s1[4], 80.f)),
                          __builtin_amdgcn_exp2f(fminf(s1[5], 80.f)));
      uint32_t c3 = cvtpk(__builtin_amdgcn_exp2f(fminf(s1[6], 80.f)),
                          __builtin_amdgcn_exp2f(fminf(s1[7], 80.f)));
      uint32_t c4 = cvtpk(__builtin_amdgcn_exp2f(fminf(s1[8], 80.f)),
                          __builtin_amdgcn_exp2f(fminf(s1[9], 80.f)));
      uint32_t c5 = cvtpk(__builtin_amdgcn_exp2f(fminf(s1[10], 80.f)),
                          __builtin_amdgcn_exp2f(fminf(s1[11], 80.f)));
      uint32_t c6 = cvtpk(__builtin_amdgcn_exp2f(fminf(s1[12], 80.f)),
                          __builtin_amdgcn_exp2f(fminf(s1[13], 80.f)));
      uint32_t c7 = cvtpk(__builtin_amdgcn_exp2f(fminf(s1[14], 80.f)),
                          __builtin_amdgcn_exp2f(fminf(s1[15], 80.f)));
      pl32swap(c0, c2); pl32swap(c1, c3); pl32swap(c4, c6); pl32swap(c5, c7);
      pf2.u[0] = c0; pf2.u[1] = c1; pf2.u[2] = c2; pf2.u[3] = c3;
      pf3.u[0] = c4; pf3.u[1] = c5; pf3.u[2] = c6; pf3.u[3] = c7;
    }

    // O += P V ; Os += P * ones.  Oa: rows=q (regs), col=lane&31 = d (+32*dt).
    __builtin_amdgcn_s_setprio(1);
#pragma unroll
    for (int kf = 0; kf < 4; kf++) {
      int g = 2 * kf + hi;
      bf16x8 pv = (kf == 0) ? pf0.v : (kf == 1) ? pf1.v : (kf == 2) ? pf2.v : pf3.v;
      bf16x8 v0 = *(const bf16x8*)&Vsm[buf][l32 * 64 + ((g ^ rsw) * 8)];
      bf16x8 v1 = *(const bf16x8*)&Vsm[buf][(32 + l32) * 64 + ((g ^ rsw) * 8)];
      Oa0 = __builtin_amdgcn_mfma_f32_32x32x16_bf16(pv, v0, Oa0, 0, 0, 0);
      Oa1 = __builtin_amdgcn_mfma_f32_32x32x16_bf16(pv, v1, Oa1, 0, 0, 0);
      Os  = __builtin_amdgcn_mfma_f32_32x32x16_bf16(pv, ones, Os, 0, 0, 0);
    }
    __builtin_amdgcn_s_setprio(0);

    __syncthreads();   // drains prefetch vmcnt + all waves done with buf
  }

  // epilogue: ctx[b*2048+s][h*64+d] bf16. q in regs: (r&3)+8*(r>>2)+4*hi.
  int bidx = bh >> 4, h = bh & 15;
#pragma unroll
  for (int r = 0; r < 16; r++) {
    float inv = 1.0f / Os[r];
    int qloc = (r & 3) + 8 * (r >> 2) + 4 * hi;
    int sidx = q0 + wv * 32 + qloc;
    size_t base = ((size_t)(bidx * SEQ) + sidx) * HID + h * HEADDIM;
    ctx[base + l32]      = f2bf(Oa0[r] * inv);
    ctx[base + 32 + l32] = f2bf(Oa1[r] * inv);
  }
}

// ---------------- output projection + bias + residual ----------------
__global__ __launch_bounds__(256) void k_oproj(const ushort* __restrict__ ctx,
                                               const ushort* __restrict__ wmat,
                                               const float* __restrict__ bo,
                                               const float* __restrict__ x,
                                               float* __restrict__ out) {
  __shared__ ushort As[128 * 32];
  __shared__ ushort Bs[128 * 32];
  int tid = threadIdx.x;
  int lane = tid & 63;
  int wv = tid >> 6;
  int quad = lane >> 4;
  int l16 = lane & 15;
  int m0 = blockIdx.x * 128;
  int n0 = blockIdx.y * 128;
  const ushort* wptr = wmat + (size_t)3 * (HID * HID) + (size_t)n0 * HID;  // Wo
  int arow = tid >> 2;
  int acol = (tid & 3) * 8;
  int wm = (wv >> 1) * 64, wn = (wv & 1) * 64;

  f32x4 acc[4][4] = {};
  for (int k0 = 0; k0 < HID; k0 += 32) {
    __syncthreads();
    for (int t = 0; t < 2; t++) {
      gl_lds16(ctx + (size_t)(m0 + t * 64 + arow) * HID + k0 + acol,
               As + t * 2048 + wv * 512);
      gl_lds16(wptr + (size_t)(t * 64 + arow) * HID + k0 + acol,
               Bs + t * 2048 + wv * 512);
    }
    __syncthreads();
    bf16x8 af[4], bfr[4];
    for (int i = 0; i < 4; i++)
      af[i] = *(const bf16x8*)&As[(wm + i * 16 + l16) * 32 + quad * 8];
    for (int n = 0; n < 4; n++)
      bfr[n] = *(const bf16x8*)&Bs[(wn + n * 16 + l16) * 32 + quad * 8];
    for (int i = 0; i < 4; i++)
      for (int n = 0; n < 4; n++)
        acc[i][n] = __builtin_amdgcn_mfma_f32_16x16x32_bf16(af[i], bfr[n], acc[i][n], 0, 0, 0);
  }
  float bv4[4];
  for (int n = 0; n < 4; n++) bv4[n] = bo[n0 + wn + n * 16 + l16];
  for (int i = 0; i < 4; i++) {
    int mrow = m0 + wm + i * 16 + quad * 4;
    for (int n = 0; n < 4; n++) {
      int col = n0 + wn + n * 16 + l16;
      for (int r = 0; r < 4; r++) {
        size_t idx = (size_t)(mrow + r) * HID + col;
        out[idx] = acc[i][n][r] + bv4[n] + x[idx];
      }
    }
  }
}

extern "C" void kernel_launch(void* const* d_in, const int* in_sizes, int n_in,
                              void* d_out, int out_size, void* d_ws, size_t ws_size,
                              hipStream_t stream) {
  const float* x    = (const float*)d_in[0];
  const float* Wq   = (const float*)d_in[1];
  const float* bq   = (const float*)d_in[2];
  const float* Wk   = (const float*)d_in[3];
  const float* bk   = (const float*)d_in[4];
  const float* Wv   = (const float*)d_in[5];
  const float* bv   = (const float*)d_in[6];
  const float* Wo   = (const float*)d_in[7];
  const float* bo   = (const float*)d_in[8];
  const float* ln_g = (const float*)d_in[9];
  const float* ln_b = (const float*)d_in[10];
  float* out = (float*)d_out;

  const size_t MB = 1024 * 1024;
  ushort* ws_w = (ushort*)d_ws;                         // weights bf16, 8 MB
  ushort* xn   = (ushort*)((char*)d_ws + 8 * MB);
  ushort* Qw   = (ushort*)((char*)d_ws + 16 * MB);
  ushort* Kw   = (ushort*)((char*)d_ws + 24 * MB);
  ushort* Vw   = (ushort*)((char*)d_ws + 32 * MB);      // transposed [bh][d][s]
  ushort* Cw   = (ushort*)((char*)d_ws + 40 * MB);

  k_cvt<<<dim3(1024, 4), 256, 0, stream>>>(Wq, Wk, Wv, Wo, ws_w);
  k_ln<<<dim3(MROWS), 256, 0, stream>>>(x, ln_g, ln_b, xn);
  k_qkv<<<dim3(32, 24), 256, 0, stream>>>(xn, ws_w, bq, bk, bv, Qw, Kw, Vw);
  k_attn<<<dim3(SEQ / 128, BATCH * NHEADS), 256, 0, stream>>>(Qw, Kw, Vw, Cw);
  k_oproj<<<dim3(32, 8), 256, 0, stream>>>(Cw, ws_w, bo, x, out);
}